// Round 1
// baseline (128.813 us; speedup 1.0000x reference)
//
#include <hip/hip_runtime.h>

// BasisFunction2D, round 11: row-progress pipelined bf2d (kill the barrier).
// R10 counters: top dispatches are harness poison-fills (2 x 289 MiB @
// ~6.3 TB/s ~= 96 us of the 123 us window) -- immovable. Our kernels ~27 us:
// stage ~12-14 us (P = 75.8 MB read once, HBM floor) then compute ~6-8 us,
// fully SERIALIZED behind a full-tile __syncthreads at 1 block/CU.
// This round overlaps them:
//  - 8 stager waves (512 thr) stage x-row-ordered (task order was already
//    row-major), 2-deep register prefetch, publish per-wave progress in LDS
//    after an lgkmcnt(0) fence. 512-B stripes preserved (R8: 128-B -> 875GB/s).
//  - 8 compute waves (b = lane -> zc stays coalesced): per-thread work split
//    into 8 single-row chunks (il x lo/hi; the bilinear lerp decomposes as
//    (1-wx)*zlerp(row gx) + wx*zlerp(row gx+1)), sorted by needed row via a
//    Batcher-8 network in registers, executed in 4 pairs, each pair gated by
//    a wave-uniform spin on min(progress). Avg start ~66% into the stage.
// Predicted: bf2d 20-22 -> 14-16 us, dur 123 -> ~116. absmax unchanged.

#define NG        16
#define NB        17              // NG+1
#define IN_X      32
#define IN_Z      32
#define OUT_DIM   64
#define BATCH     512
#define CELLS     (NB * NB)       // 289
#define CSTRIDE   133             // odd cell stride (bank spread), +1 cell = gz+1
#define ILSTRIDE  33              // per-i row stride inside a cell
#define XSTR_A    (NB * CSTRIDE)  // 2261: +1 x-row (gx+1)
#define STASKS    (CELLS * 32)    // 9248 float4-pair staging tasks, row-major
#define NSTAGE    512             // stager threads = 8 waves
#define NITER     19              // ceil(STASKS / NSTAGE)

__device__ __forceinline__ void grid_coord(float v,
                                           const float* __restrict__ borders,
                                           const float* __restrict__ inv_len,
                                           int& idx, float& w) {
    float e   = expf(-fabsf(v));
    float cdf = (v > 0.f) ? (1.f - 0.5f * e) : (0.5f * e);
    int t = (int)(cdf * 16.f);
    t = t < 0 ? 0 : (t > NG - 1 ? NG - 1 : t);
    idx = t;
    w = (v - borders[t]) * inv_len[t];
}

// pack two floats as bf16 (round-to-nearest-even), lo = a, hi = b
__device__ __forceinline__ unsigned pack_bf16(float a, float b) {
    unsigned ua = __float_as_uint(a);
    unsigned ub = __float_as_uint(b);
    ua += 0x7FFFu + ((ua >> 16) & 1u);
    ub += 0x7FFFu + ((ub >> 16) & 1u);
    return (ua >> 16) | (ub & 0xFFFF0000u);
}
__device__ __forceinline__ float bf_lo(unsigned u) {
    return __uint_as_float(u << 16);
}
__device__ __forceinline__ float bf_hi(unsigned u) {
    return __uint_as_float(u & 0xFFFF0000u);
}

// 32768 threads: gid<16384 -> x table (stores RAW idx now), else z table.
// Also zeroes out[] (32768 elements).
__global__ void precompute_kernel(const float* __restrict__ x,
                                  const float* __restrict__ z,
                                  const float* __restrict__ borders,
                                  const float* __restrict__ inv_len,
                                  float2* __restrict__ xc,   // [32*512]
                                  uint2* __restrict__ zc,    // [32*512]
                                  float* __restrict__ out) {
    const int gid = blockIdx.x * blockDim.x + threadIdx.x;
    out[gid] = 0.f;
    int idx; float w;
    if (gid < IN_X * BATCH) {
        grid_coord(x[gid], borders, inv_len, idx, w);
        xc[gid] = make_float2(w, __int_as_float(idx));          // raw gx
    } else {
        const int g = gid - IN_X * BATCH;   // g = j*512 + b
        grid_coord(z[g], borders, inv_len, idx, w);
        zc[g] = make_uint2(__float_as_uint(w), (unsigned)(idx * CSTRIDE));
    }
}

__global__ __launch_bounds__(1024, 1)
void bf2d_kernel(const float2* __restrict__ xc,
                 const uint2* __restrict__ zc,
                 const float* __restrict__ P,
                 float* __restrict__ out) {
    // lds[cell*133 + il*33 + j] = packed bf16 (P[cell,o0,i,j], P[cell,o1,i,j])
    __shared__ unsigned lds[CELLS * CSTRIDE];   // 38437 dwords = 153748 B
    __shared__ unsigned prog[8];                // per-stager-wave iters done

    const int tid = threadIdx.x;                // 1024 threads
    const int op  = blockIdx.x & 31;            // o-pair
    const int iq  = blockIdx.x >> 5;            // i-quad 0..7
    const int o0  = op * 2;

    if (tid < 8) prog[tid] = 0u;
    __syncthreads();                            // only barrier in the kernel

    if (tid < NSTAGE) {
        // ---------------- stager half: 8 waves, row-ordered ----------------
        const int wv = tid >> 6;
        volatile unsigned* vprog = prog;
        // P float index: cell*65536 + o*1024 + i*32 + j
        const float* Pb = P + (size_t)o0 * 1024 + iq * 128;

        // 2-deep software prefetch so the per-iteration lgkmcnt fence never
        // starves the load pipe (64 B/thread in flight >> BW*latency need).
        float4 a0v, b0v, a1v, b1v;
        {
            const float* g0 = Pb + (size_t)(tid >> 5) * 65536 + (tid & 31) * 4;
            a0v = *(const float4*)g0;
            b0v = *(const float4*)(g0 + 1024);
            const int k1 = tid + NSTAGE;
            const float* g1 = Pb + (size_t)(k1 >> 5) * 65536 + (k1 & 31) * 4;
            a1v = *(const float4*)g1;
            b1v = *(const float4*)(g1 + 1024);
        }
        for (int it = 0; it < NITER; ++it) {
            float4 a2v = make_float4(0.f, 0.f, 0.f, 0.f);
            float4 b2v = a2v;
            const int kp = tid + (it + 2) * NSTAGE;
            if (kp < STASKS) {
                const float* gp = Pb + (size_t)(kp >> 5) * 65536 + (kp & 31) * 4;
                a2v = *(const float4*)gp;            // o0 stripe (512-B bursts)
                b2v = *(const float4*)(gp + 1024);   // o1 stripe
            }
            const int k = tid + it * NSTAGE;
            if (k < STASKS) {
                const int c  = k >> 5;               // cell, ascending => row-major
                const int f4 = k & 31;
                unsigned* d = &lds[c * CSTRIDE + (f4 >> 3) * ILSTRIDE
                                   + ((f4 & 7) << 2)];
                d[0] = pack_bf16(a0v.x, b0v.x);
                d[1] = pack_bf16(a0v.y, b0v.y);
                d[2] = pack_bf16(a0v.z, b0v.z);
                d[3] = pack_bf16(a0v.w, b0v.w);
            }
            // publish: all this wave's ds_writes visible before prog bump
            asm volatile("s_waitcnt lgkmcnt(0)" ::: "memory");
            if ((tid & 63) == 0) vprog[wv] = (unsigned)(it + 1);
            a0v = a1v; b0v = b1v;
            a1v = a2v; b1v = b2v;
        }
        return;   // stagers exit; no further barriers exist
    }

    // ---------------- compute half: 8 waves, b = lane ----------------
    const int b = tid - NSTAGE;                  // 0..511, lane-consecutive
    const float2 xv0 = xc[(iq * 4 + 0) * BATCH + b];
    const float2 xv1 = xc[(iq * 4 + 1) * BATCH + b];
    const float2 xv2 = xc[(iq * 4 + 2) * BATCH + b];
    const float2 xv3 = xc[(iq * 4 + 3) * BATCH + b];
    const float wx0 = xv0.x, wx1 = xv1.x, wx2 = xv2.x, wx3 = xv3.x;
    const unsigned g0 = (unsigned)__float_as_int(xv0.y);
    const unsigned g1 = (unsigned)__float_as_int(xv1.y);
    const unsigned g2 = (unsigned)__float_as_int(xv2.y);
    const unsigned g3 = (unsigned)__float_as_int(xv3.y);

    // 8 chunks: key = need_row<<3 | il<<1 | hilo.  lo needs row gx (weight
    // 1-wx), hi needs row gx+1 (weight wx).  Sort ascending by needed row.
    unsigned key[8];
    key[0] = (g0 << 3) | 0u;  key[1] = ((g0 + 1u) << 3) | 1u;
    key[2] = (g1 << 3) | 2u;  key[3] = ((g1 + 1u) << 3) | 3u;
    key[4] = (g2 << 3) | 4u;  key[5] = ((g2 + 1u) << 3) | 5u;
    key[6] = (g3 << 3) | 6u;  key[7] = ((g3 + 1u) << 3) | 7u;

#define CE(i, j) { const unsigned lo_ = key[i] < key[j] ? key[i] : key[j];   \
                   const unsigned hi_ = key[i] < key[j] ? key[j] : key[i];   \
                   key[i] = lo_; key[j] = hi_; }
    // Batcher odd-even merge sort, n=8 (19 CEs), all-static indices
    CE(0,1) CE(2,3) CE(4,5) CE(6,7)
    CE(0,2) CE(1,3) CE(4,6) CE(5,7)
    CE(1,2) CE(5,6)
    CE(0,4) CE(1,5) CE(2,6) CE(3,7)
    CE(2,4) CE(3,5)
    CE(1,2) CE(3,4) CE(5,6)
#undef CE

    volatile unsigned* vprog = prog;
    const uint2* zp = zc + b;
    float accx = 0.f, accy = 0.f;
    unsigned rows_done = 0;

#pragma unroll
    for (int ph = 0; ph < 4; ++ph) {
        const unsigned kA = key[2 * ph], kB = key[2 * ph + 1];

        // wave-uniform wait: max needed row over 64 lanes (kB >= kA per lane)
        int mx = (int)kB;
#pragma unroll
        for (int off = 32; off > 0; off >>= 1) {
            const int o = __shfl_xor(mx, off);
            mx = mx > o ? mx : o;
        }
        const unsigned need = (((unsigned)mx) >> 3) + 1u;   // rows required
        if (rows_done < need) {
            for (;;) {
                unsigned m = vprog[0];
#pragma unroll
                for (int w2 = 1; w2 < 8; ++w2) {
                    const unsigned pv = vprog[w2];
                    m = pv < m ? pv : m;
                }
                // contiguous tasks done = m*512; row r ready iff (r+1)*544 <= that
                rows_done = (m * 16u) / 17u;
                if (rows_done >= need) break;
                __builtin_amdgcn_s_sleep(2);
            }
            asm volatile("" ::: "memory");
        }

        const unsigned nA = kA >> 3, nB = kB >> 3;
        const int ilA = (int)((kA >> 1) & 3u), ilB = (int)((kB >> 1) & 3u);
        const float wxA = ilA == 0 ? wx0 : ilA == 1 ? wx1 : ilA == 2 ? wx2 : wx3;
        const float wxB = ilB == 0 ? wx0 : ilB == 1 ? wx1 : ilB == 2 ? wx2 : wx3;
        const float wA = (kA & 1u) ? wxA : 1.f - wxA;
        const float wB = (kB & 1u) ? wxB : 1.f - wxB;
        const int baseA = (int)nA * XSTR_A + ilA * ILSTRIDE;
        const int baseB = (int)nB * XSTR_A + ilB * ILSTRIDE;

#pragma unroll 4
        for (int j = 0; j < IN_Z; ++j) {
            const uint2 zv = zp[j * BATCH];     // coalesced, L1/L2-resident
            const float wz = __uint_as_float(zv.x);
            const int   zo = (int)zv.y + j;
            {
                const int ba = baseA + zo;
                const unsigned q0 = lds[ba];
                const unsigned q1 = lds[ba + CSTRIDE];      // ds_read2 pair
                const float lx = bf_lo(q0) + wz * (bf_lo(q1) - bf_lo(q0));
                const float ly = bf_hi(q0) + wz * (bf_hi(q1) - bf_hi(q0));
                accx = fmaf(wA, lx, accx);
                accy = fmaf(wA, ly, accy);
            }
            {
                const int bb = baseB + zo;
                const unsigned q0 = lds[bb];
                const unsigned q1 = lds[bb + CSTRIDE];
                const float lx = bf_lo(q0) + wz * (bf_lo(q1) - bf_lo(q0));
                const float ly = bf_hi(q0) + wz * (bf_hi(q1) - bf_hi(q0));
                accx = fmaf(wB, lx, accx);
                accy = fmaf(wB, ly, accy);
            }
        }
    }

    atomicAdd(&out[o0 * BATCH + b],       accx);
    atomicAdd(&out[(o0 + 1) * BATCH + b], accy);
}

extern "C" void kernel_launch(void* const* d_in, const int* in_sizes, int n_in,
                              void* d_out, int out_size, void* d_ws, size_t ws_size,
                              hipStream_t stream) {
    const float* x       = (const float*)d_in[0];   // (32, 512)
    const float* z       = (const float*)d_in[1];   // (32, 512)
    const float* P       = (const float*)d_in[2];   // (17,17,64,32,32)
    const float* borders = (const float*)d_in[3];   // (17,)
    const float* inv_len = (const float*)d_in[4];   // (16,)
    float* out = (float*)d_out;                     // (64, 512) = 32768

    float2* xc = (float2*)d_ws;                     // 16384 float2
    uint2*  zc = (uint2*)(xc + IN_X * BATCH);       // 16384 uint2

    precompute_kernel<<<dim3(128), dim3(256), 0, stream>>>(
        x, z, borders, inv_len, xc, zc, out);

    bf2d_kernel<<<dim3(32 * 8), dim3(1024), 0, stream>>>(xc, zc, P, out);
}

// Round 3
// 125.342 us; speedup vs baseline: 1.0277x; 1.0277x over previous
//
#include <hip/hip_runtime.h>
#include <hip/hip_fp16.h>

// BasisFunction2D, round 13: R12 resubmit with the cvt_pkrtz typedef fixed
// (builtin returns __fp16 ext_vector(2), not _Float16 ext_vector(2)).
// Theory unchanged from R12: revert R11's pipeline (regressed -5.6 us);
// back to the verified R10 skeleton with ONE change: bf16-pair LDS ->
// fp16-pair LDS + packed half2 math. R10's compute phase was VALU-bound
// (~1280 scalar unpack/lerp ops vs 128 ds_read2 per thread); half2 ops cut
// the lerp chain ~20 -> 7 ops, staging pack 6 ops -> 1 (v_cvt_pkrtz).
// fp16 also IMPROVES precision vs bf16 (10 vs 7 mantissa bits).
// Layout/strides/staging identical to R10: block=(op, iq), 512-B stripes,
// CSTRIDE 133, 153.7 KB LDS, 1 block/CU, grid 256.
// Predict: dur 123.2 -> ~119, absmax 9.8e-4 -> ~2-5e-4 (fp16 confirmation).

#define NG        16
#define NB        17              // NG+1
#define IN_X      32
#define IN_Z      32
#define OUT_DIM   64
#define BATCH     512
#define CELLS     (NB * NB)       // 289
#define CSTRIDE   133             // 4*33 + 1: odd cell stride (bank spread)
#define ILSTRIDE  33              // per-i row stride inside a cell
#define XSTR_A    (NB * CSTRIDE)  // 2261: gx -> +17 cells
#define STASKS    (CELLS * 32)    // 9248 float4-pair staging tasks

typedef __fp16 h2v __attribute__((ext_vector_type(2)));

__device__ __forceinline__ void grid_coord(float v,
                                           const float* __restrict__ borders,
                                           const float* __restrict__ inv_len,
                                           int& idx, float& w) {
    float e   = expf(-fabsf(v));
    float cdf = (v > 0.f) ? (1.f - 0.5f * e) : (0.5f * e);
    int t = (int)(cdf * 16.f);
    t = t < 0 ? 0 : (t > NG - 1 ? NG - 1 : t);
    idx = t;
    w = (v - borders[t]) * inv_len[t];
}

// pack two floats as fp16 pair (v_cvt_pkrtz, 1 instr): lo = a, hi = b
__device__ __forceinline__ unsigned pack_h2(float a, float b) {
    h2v v = __builtin_amdgcn_cvt_pkrtz(a, b);
    return __builtin_bit_cast(unsigned, v);
}
__device__ __forceinline__ __half2 u2h(unsigned u) {
    return __builtin_bit_cast(__half2, u);
}

// 32768 threads: gid<16384 -> x table, else z table ([j][b], coalesced reads).
// Also zeroes out[] (32768 elements). Weights stored PRE-PACKED as half2.
__global__ void precompute_kernel(const float* __restrict__ x,
                                  const float* __restrict__ z,
                                  const float* __restrict__ borders,
                                  const float* __restrict__ inv_len,
                                  uint2* __restrict__ xc,    // [32*512]
                                  uint2* __restrict__ zc,    // [32*512]
                                  float* __restrict__ out) {
    const int gid = blockIdx.x * blockDim.x + threadIdx.x;
    out[gid] = 0.f;
    int idx; float w;
    if (gid < IN_X * BATCH) {
        grid_coord(x[gid], borders, inv_len, idx, w);
        xc[gid] = make_uint2(pack_h2(w, w), (unsigned)(idx * XSTR_A));
    } else {
        const int g = gid - IN_X * BATCH;   // g = j*512 + b (z's own layout)
        grid_coord(z[g], borders, inv_len, idx, w);
        zc[g] = make_uint2(pack_h2(w, w), (unsigned)(idx * CSTRIDE));
    }
}

__global__ __launch_bounds__(1024, 1)
void bf2d_kernel(const uint2* __restrict__ xc,
                 const uint2* __restrict__ zc,
                 const float* __restrict__ P,
                 float* __restrict__ out) {
    // lds[cell*133 + il*33 + j] = half2 (P[cell,o0,i,j], P[cell,o1,i,j])
    __shared__ unsigned lds[CELLS * CSTRIDE];   // 38437 dwords = 153748 B

    const int tid = threadIdx.x;                // 1024 threads
    const int op  = blockIdx.x & 31;            // o-pair
    const int iq  = blockIdx.x >> 5;            // i-quad 0..7
    const int o0  = op * 2;

    // ---- stage P[:, o0:o0+2, iq*4:(iq+1)*4, :] : 512-B stripes per (cell,o)
    // P float index: cell*65536 + o*1024 + i*32 + j
    const float* Pb = P + (size_t)o0 * 1024 + iq * 128;
    #pragma unroll
    for (int it = 0; it < 10; ++it) {
        const int k = tid + it * 1024;
        if (k < STASKS) {
            const int c  = k >> 5;
            const int f4 = k & 31;              // il = f4>>3, j4 = (f4&7)*4
            const float* g = Pb + (size_t)c * 65536 + f4 * 4;
            const float4 a = *(const float4*)g;           // o0 stripe
            const float4 b = *(const float4*)(g + 1024);  // o1 stripe
            unsigned* d = &lds[c * CSTRIDE + (f4 >> 3) * ILSTRIDE
                               + ((f4 & 7) << 2)];
            d[0] = pack_h2(a.x, b.x);
            d[1] = pack_h2(a.y, b.y);
            d[2] = pack_h2(a.z, b.z);
            d[3] = pack_h2(a.w, b.w);
        }
    }
    __syncthreads();

    // ---- per-thread: batch b, two local i's (il = 2*ih, 2*ih+1) ----
    const int b  = tid & (BATCH - 1);
    const int ih = tid >> 9;                    // 0 or 1
    const int il0 = 2 * ih, il1 = 2 * ih + 1;

    const uint2 x0 = xc[(iq * 4 + il0) * BATCH + b];
    const uint2 x1 = xc[(iq * 4 + il1) * BATCH + b];
    const __half2 wx0 = u2h(x0.x), wx1 = u2h(x1.x);
    const int xo0 = (int)x0.y + il0 * ILSTRIDE;
    const int xo1 = (int)x1.y + il1 * ILSTRIDE;

    const uint2* zp = zc + b;
    __half2 acc0 = __float2half2_rn(0.f);       // il0 accumulator (o0,o1)
    __half2 acc1 = __float2half2_rn(0.f);       // il1 accumulator
    #pragma unroll 4
    for (int j = 0; j < IN_Z; ++j) {
        const uint2 zv = zp[j * BATCH];         // coalesced, L2-resident
        const __half2 wz = u2h(zv.x);
        const int     zo = (int)zv.y + j;
        {
            const int base = xo0 + zo;
            const __half2 q0 = u2h(lds[base]);
            const __half2 q1 = u2h(lds[base + CSTRIDE]);          // read2
            const __half2 v0 = u2h(lds[base + XSTR_A]);
            const __half2 v1 = u2h(lds[base + XSTR_A + CSTRIDE]); // read2
            const __half2 zlo = __hfma2(wz, __hsub2(q1, q0), q0);
            const __half2 zhi = __hfma2(wz, __hsub2(v1, v0), v0);
            acc0 = __hadd2(acc0, __hfma2(wx0, __hsub2(zhi, zlo), zlo));
        }
        {
            const int base = xo1 + zo;
            const __half2 q0 = u2h(lds[base]);
            const __half2 q1 = u2h(lds[base + CSTRIDE]);
            const __half2 v0 = u2h(lds[base + XSTR_A]);
            const __half2 v1 = u2h(lds[base + XSTR_A + CSTRIDE]);
            const __half2 zlo = __hfma2(wz, __hsub2(q1, q0), q0);
            const __half2 zhi = __hfma2(wz, __hsub2(v1, v0), v0);
            acc1 = __hadd2(acc1, __hfma2(wx1, __hsub2(zhi, zlo), zlo));
        }
    }

    // f32 combine of the two per-il half2 partial sums (8 ops, negligible)
    const float accx = __low2float(acc0)  + __low2float(acc1);
    const float accy = __high2float(acc0) + __high2float(acc1);

    atomicAdd(&out[o0 * BATCH + b],       accx);
    atomicAdd(&out[(o0 + 1) * BATCH + b], accy);
}

extern "C" void kernel_launch(void* const* d_in, const int* in_sizes, int n_in,
                              void* d_out, int out_size, void* d_ws, size_t ws_size,
                              hipStream_t stream) {
    const float* x       = (const float*)d_in[0];   // (32, 512)
    const float* z       = (const float*)d_in[1];   // (32, 512)
    const float* P       = (const float*)d_in[2];   // (17,17,64,32,32)
    const float* borders = (const float*)d_in[3];   // (17,)
    const float* inv_len = (const float*)d_in[4];   // (16,)
    float* out = (float*)d_out;                     // (64, 512) = 32768

    uint2* xc = (uint2*)d_ws;                       // 16384 uint2
    uint2* zc = xc + IN_X * BATCH;                  // 16384 uint2

    precompute_kernel<<<dim3(128), dim3(256), 0, stream>>>(
        x, z, borders, inv_len, xc, zc, out);

    bf2d_kernel<<<dim3(32 * 8), dim3(1024), 0, stream>>>(xc, zc, P, out);
}